// Round 2
// baseline (743.336 us; speedup 1.0000x reference)
//
#include <hip/hip_runtime.h>

#define NN 1024
#define LL 50
#define EE 128
#define RR 13
#define NEGM -9.0e15f
#define PAD 4

// Kernel 1: h[n][e] = sum_l item[n][l][e] / session_len[n]  (fp32, into ws)
// 8 rows per 256-thread block; 32 lanes x float4 per row.
__global__ void __launch_bounds__(256)
hpool_kernel(const float* __restrict__ item, const float* __restrict__ slen,
             float* __restrict__ h) {
    const int n = blockIdx.x * 8 + (threadIdx.x >> 5);
    const int e4 = (threadIdx.x & 31) * 4;
    const float* p = item + (size_t)n * (LL * EE) + e4;
    float4 acc = {0.f, 0.f, 0.f, 0.f};
#pragma unroll
    for (int l = 0; l < LL; ++l) {
        const float4 v = *(const float4*)(p + (size_t)l * EE);
        acc.x += v.x; acc.y += v.y; acc.z += v.z; acc.w += v.w;
    }
    const float inv = 1.f / slen[n];
    float4 r; r.x = acc.x * inv; r.y = acc.y * inv; r.z = acc.z * inv; r.w = acc.w * inv;
    *(float4*)(h + n * EE + e4) = r;
}

// Kernel 2: one block per row i. Bucket j by relation type (octet-uniform r),
// one 8-lane octet per pair computes only the SELECTED relation score
// (coalesced 512B stamp-row reads), masked softmax, out[i] = sum_j p_j h_j.
__global__ void __launch_bounds__(256)
attn_kernel(const int* __restrict__ ovl,
            const float* __restrict__ stamp,
            const float* __restrict__ aw,
            const float* __restrict__ tw,
            const float* __restrict__ h,
            float* __restrict__ out) {
    __shared__ float w_lds[RR][EE + PAD];   // h_i[e] * a_w[e][r]
    __shared__ float t_lds[RR][EE + PAD];   // t_w[e][r]
    __shared__ float score[NN];
    __shared__ unsigned short jlist[NN];
    __shared__ unsigned char rty[NN];
    __shared__ int cnt[RR];
    __shared__ int ofs[RR + 1];
    __shared__ float red[4];
    __shared__ float pacc[8][EE];

    const int i = blockIdx.x;
    const int tid = threadIdx.x;

    // ---- phase 0: per-row fp32 tables ----
    for (int idx = tid; idx < RR * EE; idx += 256) {
        const int e = idx & (EE - 1);
        const int r = idx >> 7;
        w_lds[r][e] = h[i * EE + e] * aw[e * RR + r];
        t_lds[r][e] = tw[e * RR + r];
    }
    if (tid < RR) cnt[tid] = 0;
    __syncthreads();

    // ---- phase 1: bucket j by relation; masked -> NEGM ----
    for (int j = tid; j < NN; j += 256) {
        const int ov = ovl[i * NN + j];
        rty[j] = (unsigned char)ov;
        if (ov >= 1) atomicAdd(&cnt[min(ov, RR) - 1], 1);
        else score[j] = NEGM;
    }
    __syncthreads();
    if (tid == 0) {
        int s = 0;
        for (int r = 0; r < RR; ++r) { ofs[r] = s; s += cnt[r]; }
        ofs[RR] = s;
    }
    __syncthreads();
    const int M = ofs[RR];
    for (int j = tid; j < NN; j += 256) {
        const int ov = rty[j];
        if (ov >= 1) {
            const int pos = atomicAdd(&ofs[min(ov, RR) - 1], 1);
            jlist[pos] = (unsigned short)j;
        }
    }
    __syncthreads();

    // ---- phase 2: selected-relation score, one octet (8 lanes) per pair ----
    {
        const int oct = tid >> 3;
        const int sub = tid & 7;
        const float* srow = stamp + (size_t)i * (NN * EE);
        for (int k = oct; k < M; k += 32) {
            const int j = jlist[k];
            const int r = (int)rty[j] - 1;
            const float4* __restrict__ sp = (const float4*)(srow + (size_t)j * EE) + sub * 4;
            const float4* __restrict__ hp = (const float4*)(h + j * EE) + sub * 4;
            const float* __restrict__ wp = &w_lds[r][sub * 16];
            const float* __restrict__ tp = &t_lds[r][sub * 16];
            float a0 = 0.f, a1 = 0.f;
#pragma unroll
            for (int q = 0; q < 4; ++q) {
                const float4 s4 = sp[q];
                const float4 h4 = hp[q];
                const float4 w4 = *(const float4*)(wp + q * 4);
                const float4 t4 = *(const float4*)(tp + q * 4);
                a0 = fmaf(w4.x, h4.x, a0); a1 = fmaf(t4.x, s4.x, a1);
                a0 = fmaf(w4.y, h4.y, a0); a1 = fmaf(t4.y, s4.y, a1);
                a0 = fmaf(w4.z, h4.z, a0); a1 = fmaf(t4.z, s4.z, a1);
                a0 = fmaf(w4.w, h4.w, a0); a1 = fmaf(t4.w, s4.w, a1);
            }
            float acc = a0 + a1;
            acc += __shfl_xor(acc, 1);
            acc += __shfl_xor(acc, 2);
            acc += __shfl_xor(acc, 4);
            if (sub == 0) score[j] = (acc >= 0.f) ? acc : 0.2f * acc;  // LeakyReLU(0.2)
        }
    }
    __syncthreads();

    // ---- phase 3: masked softmax over j ----
    const int lane = tid & 63;
    const int wid = tid >> 6;
    float m = -INFINITY;
    for (int j = tid; j < NN; j += 256) m = fmaxf(m, score[j]);
#pragma unroll
    for (int o = 32; o; o >>= 1) m = fmaxf(m, __shfl_xor(m, o));
    if (lane == 0) red[wid] = m;
    __syncthreads();
    m = fmaxf(fmaxf(red[0], red[1]), fmaxf(red[2], red[3]));
    __syncthreads();  // red reused
    float s = 0.f;
    for (int j = tid; j < NN; j += 256) {
        const float ex = __expf(score[j] - m);  // masked: underflows to 0
        score[j] = ex;
        s += ex;
    }
#pragma unroll
    for (int o = 32; o; o >>= 1) s += __shfl_xor(s, o);
    if (lane == 0) red[wid] = s;
    __syncthreads();
    const float inv = 1.f / ((red[0] + red[1]) + (red[2] + red[3]));

    // ---- phase 4: out[i] = inv * sum_j ex_j h_j (8 j-slices x 32 lanes x float4) ----
    {
        const int e4 = (tid & 31) * 4;
        const int sl = tid >> 5;  // 0..7
        float4 acc = {0.f, 0.f, 0.f, 0.f};
        const int j0 = sl * (NN / 8);
        for (int j = j0; j < j0 + NN / 8; ++j) {
            const float ex = score[j];
            const float4 h4 = *(const float4*)(h + j * EE + e4);
            acc.x = fmaf(ex, h4.x, acc.x);
            acc.y = fmaf(ex, h4.y, acc.y);
            acc.z = fmaf(ex, h4.z, acc.z);
            acc.w = fmaf(ex, h4.w, acc.w);
        }
        *(float4*)&pacc[sl][e4] = acc;
    }
    __syncthreads();
    if (tid < EE) {
        float v = 0.f;
#pragma unroll
        for (int sl = 0; sl < 8; ++sl) v += pacc[sl][tid];
        out[i * EE + tid] = v * inv;
    }
}

extern "C" void kernel_launch(void* const* d_in, const int* in_sizes, int n_in,
                              void* d_out, int out_size, void* d_ws, size_t ws_size,
                              hipStream_t stream) {
    const float* item  = (const float*)d_in[0];
    const int*   ovl   = (const int*)d_in[1];
    // d_in[2] "matrix" is unused by the reference
    const float* stamp = (const float*)d_in[3];
    const float* slen  = (const float*)d_in[4];
    const float* aw    = (const float*)d_in[5];
    const float* tw    = (const float*)d_in[6];
    float* h = (float*)d_ws;            // 1024*128 fp32 = 512 KB scratch
    float* out = (float*)d_out;

    hpool_kernel<<<NN / 8, 256, 0, stream>>>(item, slen, h);
    attn_kernel<<<NN, 256, 0, stream>>>(ovl, stamp, aw, tw, h, out);
}